// Round 7
// baseline (546.788 us; speedup 1.0000x reference)
//
#include <hip/hip_runtime.h>
#include <math.h>

#define NE 32
#define NN 8
#define EMB 256
#define TPS 32
#define E_SAME 480
#define E_ANTI 512
#define E_NE 256

// ---- ws layout (shorts) ----
#define AU1_OFF 0        // 6  x 512 : u_w1^T K=32 A-frags, idx (t*2+mt)
#define AU2_OFF 3072     // 12 x 256 : u_w2^T K=16 A-frags, idx (t*4+mt*2+ks)
#define AW1_OFF 6144     // 12 x 256 : w_w1^T
#define AW2_OFF 9216     // 12 x 256 : w_w2^T
#define H1T_OFF 12288    // 48 x 512 : h_w1^T K=32, idx (t*16+mt*8+ks)
#define H2T_OFF 36864    // 12 x 256 : h_w2^T K=16, idx (t*4+mt*2+ks)
#define BIAS_OFF 39936   // 576 bf16 : [L][t][32], L: u_b1,u_b2,w_b1,w_b2,h_b1,h_b2
#define G1_OFF 40512     // 176 x 512: g_w1 B-frags K=32, idx (nt*11+ks)
#define G2_OFF 130624    // 128 x 512: g_w2 B-frags K=32, idx (nt*8+ks)
// total 196160 shorts = 392320 B

typedef float f32x4 __attribute__((ext_vector_type(4)));
typedef short s16x4 __attribute__((ext_vector_type(4)));
typedef short s16x8 __attribute__((ext_vector_type(8)));

__device__ __forceinline__ short f2bf(float x) {
    unsigned u = __builtin_bit_cast(unsigned, x);
    u += 0x7fffu + ((u >> 16) & 1u);
    return (short)(u >> 16);
}
__device__ __forceinline__ float bf2f(short h) {
    unsigned u = ((unsigned)(unsigned short)h) << 16;
    return __builtin_bit_cast(float, u);
}
__device__ __forceinline__ float fast_tanh(float x) {
    float e = __builtin_amdgcn_exp2f(x * 2.8853900817779268f);
    return 1.f - 2.f * __builtin_amdgcn_rcpf(e + 1.f);
}
__device__ __forceinline__ s16x8 pack8(float4 a, float4 b) {
    s16x8 r = { f2bf(a.x), f2bf(a.y), f2bf(a.z), f2bf(a.w),
                f2bf(b.x), f2bf(b.y), f2bf(b.z), f2bf(b.w) };
    return r;
}
__device__ __forceinline__ f32x4 mfma32(s16x8 a, s16x8 b, f32x4 c) {
    return __builtin_amdgcn_mfma_f32_16x16x32_bf16(a, b, c, 0, 0, 0);
}
// 16x16x16 bf16: C/D layout == B layout -> chained layers need no lane shuffles.
__device__ __forceinline__ f32x4 mfma16(s16x4 a, s16x4 b, f32x4 c) {
#if __has_builtin(__builtin_amdgcn_mfma_f32_16x16x16bf16_1k)
    return __builtin_amdgcn_mfma_f32_16x16x16bf16_1k(a, b, c, 0, 0, 0);
#else
    asm volatile("v_mfma_f32_16x16x16_bf16 %0, %1, %2, %0" : "+v"(c) : "v"(a), "v"(b));
    return c;
#endif
}

__global__ void prep_weights(const float* __restrict__ u_w1, const float* __restrict__ u_w2,
                             const float* __restrict__ w_w1, const float* __restrict__ w_w2,
                             const float* __restrict__ h_w1, const float* __restrict__ h_w2,
                             const float* __restrict__ u_b1, const float* __restrict__ u_b2,
                             const float* __restrict__ w_b1, const float* __restrict__ w_b2,
                             const float* __restrict__ h_b1, const float* __restrict__ h_b2,
                             const float* __restrict__ g_w1, const float* __restrict__ g_w2,
                             short* __restrict__ wsb)
{
    int tile = blockIdx.x, lane = threadIdx.x;
    int g = lane >> 4, q = lane & 15;
    if (tile < 6) {                         // Au1: K=32 A-frag of u_w1^T
        int t = tile >> 1, mt = tile & 1;
        const float* src = u_w1 + t * 1024;
        short* dst = wsb + AU1_OFF + tile * 512 + lane * 8;
        #pragma unroll
        for (int i = 0; i < 8; ++i) dst[i] = f2bf(src[(8 * g + i) * 32 + mt * 16 + q]);
    } else if (tile < 42) {                 // Au2/Aw1/Aw2: K=16 A-frags
        int m = (tile - 6) / 12, idx = (tile - 6) % 12;
        int mt = (idx >> 1) & 1, ks = idx & 1, t = idx >> 2;
        const float* mp = (m == 0) ? u_w2 : (m == 1) ? w_w1 : w_w2;
        const float* src = mp + t * 1024;
        short* dst = wsb + AU2_OFF + m * 3072 + idx * 256 + lane * 4;
        #pragma unroll
        for (int i = 0; i < 4; ++i) dst[i] = f2bf(src[(ks * 16 + 4 * g + i) * 32 + mt * 16 + q]);
    } else if (tile < 90) {                 // h1T: K=32 A-frags
        int idx = tile - 42;
        int t = idx >> 4, r = idx & 15, mt = r >> 3, ks = r & 7;
        const float* src = h_w1 + t * 8192;
        short* dst = wsb + H1T_OFF + idx * 512 + lane * 8;
        #pragma unroll
        for (int i = 0; i < 8; ++i) dst[i] = f2bf(src[(ks * 32 + 8 * g + i) * 32 + mt * 16 + q]);
    } else if (tile < 102) {                // h2T: K=16 A-frags
        int idx = tile - 90;
        int t = idx >> 2, mt = (idx >> 1) & 1, ks = idx & 1;
        const float* src = h_w2 + t * 1024;
        short* dst = wsb + H2T_OFF + idx * 256 + lane * 4;
        #pragma unroll
        for (int i = 0; i < 4; ++i) dst[i] = f2bf(src[(ks * 16 + 4 * g + i) * 32 + mt * 16 + q]);
    } else if (tile == 102) {               // biases -> bf16 [L][t][32]
        const float* bsrc[6] = {u_b1, u_b2, w_b1, w_b2, h_b1, h_b2};
        for (int j = lane; j < 576; j += 64)
            wsb[BIAS_OFF + j] = f2bf(bsrc[j / 96][j % 96]);
    } else if (tile < 279) {                // G1 B-frags
        int idx = tile - 103, nt = idx / 11, ks = idx % 11;
        short* dst = wsb + G1_OFF + idx * 512 + lane * 8;
        #pragma unroll
        for (int i = 0; i < 8; ++i)
            dst[i] = f2bf(g_w1[(size_t)(ks * 32 + 8 * g + i) * 256 + nt * 16 + q]);
    } else {                                // G2 B-frags
        int idx = tile - 279;
        short* dst = wsb + G2_OFF + idx * 512 + lane * 8;
        int nt = idx >> 3, ks = idx & 7;
        #pragma unroll
        for (int i = 0; i < 8; ++i)
            dst[i] = f2bf(g_w2[(size_t)(ks * 32 + 8 * g + i) * 256 + nt * 16 + q]);
    }
}

// Load one 16-edge tile's operands (clamped index for padded tiles; loads are
// always in-bounds, padded results are discarded via LIVE guard).
#define LOAD_TILE(V0, V1, RL, RH, SE, RE, TIDX)                                   \
{                                                                                 \
    int ct_ = (TIDX) < real ? (TIDX) : real - 1;                                  \
    const float* fp_ = ft + ((size_t)b * cnt + ct_ * 16 + q) * TPS;               \
    V0 = *(const float4*)(fp_ + 8 * g);                                           \
    V1 = *(const float4*)(fp_ + 8 * g + 4);                                       \
    RL = *(const float4*)(fp_ + 4 * g);                                           \
    RH = *(const float4*)(fp_ + 16 + 4 * g);                                      \
    SE = snd[ct_ * 16 + q];                                                       \
    RE = rcv[ct_ * 16 + q];                                                       \
}

// One 16-edge tile through u/w MLPs + scatter. Body identical to the R6-verified
// sequence; LIVE is wave-uniform (skip scatter for padded tiles).
#define TILE_MLP(V0, V1, RL, RH, SE, RE, LIVE)                                    \
{                                                                                 \
    s16x8 B32 = pack8(V0, V1);                                                    \
    f32x4 c0 = {0.f,0.f,0.f,0.f}, c1 = {0.f,0.f,0.f,0.f};                         \
    c0 = mfma32(Au1_0, B32, c0);                                                  \
    c1 = mfma32(Au1_1, B32, c1);                                                  \
    s16x4 p0, p1;                                                                 \
    _Pragma("unroll")                                                             \
    for (int r = 0; r < 4; ++r) {                                                 \
        p0[r] = f2bf(fast_tanh(c0[r] + bf2f(bb1l[r])));                           \
        p1[r] = f2bf(fast_tanh(c1[r] + bf2f(bb1h[r])));                           \
    }                                                                             \
    f32x4 d0 = {0.f,0.f,0.f,0.f}, d1 = {0.f,0.f,0.f,0.f};                         \
    d0 = mfma16(Au2_[0], p0, d0); d0 = mfma16(Au2_[1], p1, d0);                   \
    d1 = mfma16(Au2_[2], p0, d1); d1 = mfma16(Au2_[3], p1, d1);                   \
    const float* rlp_ = (const float*)&RL; const float* rhp_ = (const float*)&RH; \
    _Pragma("unroll")                                                             \
    for (int r = 0; r < 4; ++r) {                                                 \
        p0[r] = f2bf(rlp_[r] + d0[r] + bf2f(bb2l[r]));                            \
        p1[r] = f2bf(rhp_[r] + d1[r] + bf2f(bb2h[r]));                            \
    }                                                                             \
    d0 = (f32x4){0.f,0.f,0.f,0.f}; d1 = (f32x4){0.f,0.f,0.f,0.f};                 \
    d0 = mfma16(Aw1_[0], p0, d0); d0 = mfma16(Aw1_[1], p1, d0);                   \
    d1 = mfma16(Aw1_[2], p0, d1); d1 = mfma16(Aw1_[3], p1, d1);                   \
    _Pragma("unroll")                                                             \
    for (int r = 0; r < 4; ++r) {                                                 \
        p0[r] = f2bf(fast_tanh(d0[r] + bf2f(bb3l[r])));                           \
        p1[r] = f2bf(fast_tanh(d1[r] + bf2f(bb3h[r])));                           \
    }                                                                             \
    d0 = (f32x4){0.f,0.f,0.f,0.f}; d1 = (f32x4){0.f,0.f,0.f,0.f};                 \
    d0 = mfma16(Aw2_[0], p0, d0); d0 = mfma16(Aw2_[1], p1, d0);                   \
    d1 = mfma16(Aw2_[2], p0, d1); d1 = mfma16(Aw2_[3], p1, d1);                   \
    if (LIVE) {                                                                   \
        s16x4 hlo = *(const s16x4*)(hxt + (SE) * 36 + 4 * g);                     \
        s16x4 hhi = *(const s16x4*)(hxt + (SE) * 36 + 16 + 4 * g);                \
        float* zr = z_s + (RE) * 97 + zc0 + 4 * g;                                \
        _Pragma("unroll")                                                         \
        for (int r = 0; r < 4; ++r) {                                             \
            atomicAdd(zr + r,      (d0[r] + bf2f(bb4l[r])) * bf2f(hlo[r]));       \
            atomicAdd(zr + 16 + r, (d1[r] + bf2f(bb4h[r])) * bf2f(hhi[r]));       \
        }                                                                         \
    }                                                                             \
}

// LDS: f bf16 [32][356] = 22784 ; z f32 [32][97] = 12416 ; hx bf16 [72][36] = 5184
// phase E: H bf16 [32][260] = 16640 overlays z+hx. Total 40384 B -> 4 blocks/CU.
__launch_bounds__(256, 4)
__global__ void gnn_kernel(
    const float* __restrict__ elec, const float* __restrict__ nuc,
    const float* __restrict__ fs,  const float* __restrict__ fa,  const float* __restrict__ fn,
    const float* __restrict__ g_b1, const float* __restrict__ g_b2,
    const int* __restrict__ ss, const int* __restrict__ rs,
    const int* __restrict__ sa, const int* __restrict__ ra,
    const int* __restrict__ sn, const int* __restrict__ rn,
    const short* __restrict__ wsb,
    float* __restrict__ out)
{
    __shared__ __align__(16) char smem[40384];
    short* f_s  = (short*)smem;                  // [32][356]
    float* z_s  = (float*)(smem + 22784);        // [32][97]
    short* hx_s = (short*)(smem + 35200);        // [72][36]
    short* H_s  = (short*)(smem + 22784);        // [32][260] (phase E overlay)

    const int tid  = threadIdx.x;
    const int b    = blockIdx.x;
    const int lane = tid & 63, wv = tid >> 6;
    const int g    = lane >> 4, q = lane & 15;

    // ---------- Phase A: hx^T = h_w2^T @ tanh(h_w1^T @ X^T + b1) + b2 ----------
    if (wv > 0)
        for (int i = tid - 64; i < 32 * 97; i += 192) z_s[i] = 0.f;

    #pragma unroll 1
    for (int task = wv; task < 5; task += 4) {
        int t, nt;
        if (task < 4) { t = task >> 1; nt = task & 1; }
        else          { t = 2; nt = 0; }
        const float* rowp = (t < 2) ? elec + ((size_t)b * NE + nt * 16 + q) * EMB
                                    : nuc  + ((size_t)b * NN + (q < 8 ? q : 7)) * EMB;
        f32x4 c0 = {0.f, 0.f, 0.f, 0.f}, c1 = {0.f, 0.f, 0.f, 0.f};
        const short* wA = wsb + H1T_OFF + t * 16 * 512;
        #pragma unroll
        for (int ks = 0; ks < 8; ++ks) {
            float4 v0 = *(const float4*)(rowp + 32 * ks + 8 * g);
            float4 v1 = *(const float4*)(rowp + 32 * ks + 8 * g + 4);
            s16x8 Bf = pack8(v0, v1);
            if (t == 0) {   // stash elec bf16 into f cols 0..255
                int off = (nt * 16 + q) * 356 + 32 * ks + 8 * g;
                *(s16x4*)(f_s + off)     = __builtin_shufflevector(Bf, Bf, 0, 1, 2, 3);
                *(s16x4*)(f_s + off + 4) = __builtin_shufflevector(Bf, Bf, 4, 5, 6, 7);
            }
            s16x8 a0 = *(const s16x8*)(wA + ks * 512 + lane * 8);
            s16x8 a1 = *(const s16x8*)(wA + (8 + ks) * 512 + lane * 8);
            c0 = mfma32(a0, Bf, c0);
            c1 = mfma32(a1, Bf, c1);
        }
        s16x4 b1l = *(const s16x4*)(wsb + BIAS_OFF + (12 + t) * 32 + 4 * g);
        s16x4 b1h = *(const s16x4*)(wsb + BIAS_OFF + (12 + t) * 32 + 16 + 4 * g);
        s16x4 p0, p1;
        #pragma unroll
        for (int r = 0; r < 4; ++r) {
            p0[r] = f2bf(fast_tanh(c0[r] + bf2f(b1l[r])));
            p1[r] = f2bf(fast_tanh(c1[r] + bf2f(b1h[r])));
        }
        const short* wA2 = wsb + H2T_OFF + t * 4 * 256;
        f32x4 d0 = {0.f, 0.f, 0.f, 0.f}, d1 = {0.f, 0.f, 0.f, 0.f};
        d0 = mfma16(*(const s16x4*)(wA2 + 0 * 256 + lane * 4), p0, d0);
        d0 = mfma16(*(const s16x4*)(wA2 + 1 * 256 + lane * 4), p1, d0);
        d1 = mfma16(*(const s16x4*)(wA2 + 2 * 256 + lane * 4), p0, d1);
        d1 = mfma16(*(const s16x4*)(wA2 + 3 * 256 + lane * 4), p1, d1);
        if (t < 2 || q < 8) {
            s16x4 b2l = *(const s16x4*)(wsb + BIAS_OFF + (15 + t) * 32 + 4 * g);
            s16x4 b2h = *(const s16x4*)(wsb + BIAS_OFF + (15 + t) * 32 + 16 + 4 * g);
            s16x4 w0, w1;
            #pragma unroll
            for (int r = 0; r < 4; ++r) {
                w0[r] = f2bf(d0[r] + bf2f(b2l[r]));
                w1[r] = f2bf(d1[r] + bf2f(b2h[r]));
            }
            int row = t * 32 + nt * 16 + q;
            *(s16x4*)(hx_s + row * 36 + 4 * g)      = w0;
            *(s16x4*)(hx_s + row * 36 + 16 + 4 * g) = w1;
        }
    }
    __syncthreads();

    // ---------- Phase C: edge MLPs, 2 tiles per iteration + 1-deep pair prefetch ----------
    #pragma unroll 1
    for (int t = 0; t < 3; ++t) {
        const float* ft; const int* snd; const int* rcv; int cnt, zc0;
        if (t == 0)      { ft = fs; snd = ss; rcv = rs; cnt = E_SAME; zc0 = 32; }
        else if (t == 1) { ft = fa; snd = sa; rcv = ra; cnt = E_ANTI; zc0 = 64; }
        else             { ft = fn; snd = sn; rcv = rn; cnt = E_NE;   zc0 = 0;  }
        s16x8 Au1_0 = *(const s16x8*)(wsb + AU1_OFF + (t * 2 + 0) * 512 + lane * 8);
        s16x8 Au1_1 = *(const s16x8*)(wsb + AU1_OFF + (t * 2 + 1) * 512 + lane * 8);
        s16x4 Au2_[4], Aw1_[4], Aw2_[4];
        #pragma unroll
        for (int i = 0; i < 4; ++i) {
            Au2_[i] = *(const s16x4*)(wsb + AU2_OFF + (t * 4 + i) * 256 + lane * 4);
            Aw1_[i] = *(const s16x4*)(wsb + AW1_OFF + (t * 4 + i) * 256 + lane * 4);
            Aw2_[i] = *(const s16x4*)(wsb + AW2_OFF + (t * 4 + i) * 256 + lane * 4);
        }
        s16x4 bb1l = *(const s16x4*)(wsb + BIAS_OFF + (0 + t) * 32 + 4 * g);
        s16x4 bb1h = *(const s16x4*)(wsb + BIAS_OFF + (0 + t) * 32 + 16 + 4 * g);
        s16x4 bb2l = *(const s16x4*)(wsb + BIAS_OFF + (3 + t) * 32 + 4 * g);
        s16x4 bb2h = *(const s16x4*)(wsb + BIAS_OFF + (3 + t) * 32 + 16 + 4 * g);
        s16x4 bb3l = *(const s16x4*)(wsb + BIAS_OFF + (6 + t) * 32 + 4 * g);
        s16x4 bb3h = *(const s16x4*)(wsb + BIAS_OFF + (6 + t) * 32 + 16 + 4 * g);
        s16x4 bb4l = *(const s16x4*)(wsb + BIAS_OFF + (9 + t) * 32 + 4 * g);
        s16x4 bb4h = *(const s16x4*)(wsb + BIAS_OFF + (9 + t) * 32 + 16 + 4 * g);
        const short* hxt = hx_s + t * 32 * 36;

        const int real  = cnt >> 4;            // 30, 32, 16
        const int npair = (real + 7) >> 3;     // pairs per wave: 4, 4, 2

        float4 v0A, v1A, rlA, rhA, v0B, v1B, rlB, rhB;
        float4 n0A = {0,0,0,0}, n1A = {0,0,0,0}, nlA = {0,0,0,0}, nhA = {0,0,0,0};
        float4 n0B = {0,0,0,0}, n1B = {0,0,0,0}, nlB = {0,0,0,0}, nhB = {0,0,0,0};
        int seA, reA, seB, reB;
        int nsA = 0, nrA = 0, nsB = 0, nrB = 0;
        int tA = wv, tB = wv + 4;
        LOAD_TILE(v0A, v1A, rlA, rhA, seA, reA, tA);
        LOAD_TILE(v0B, v1B, rlB, rhB, seB, reB, tB);

        #pragma unroll 1
        for (int j = 0; j < npair; ++j) {
            int tA2 = wv + 8 * (j + 1), tB2 = tA2 + 4;
            if (j + 1 < npair) {   // prefetch next pair
                LOAD_TILE(n0A, n1A, nlA, nhA, nsA, nrA, tA2);
                LOAD_TILE(n0B, n1B, nlB, nhB, nsB, nrB, tB2);
            }
            TILE_MLP(v0A, v1A, rlA, rhA, seA, reA, (tA < real));
            TILE_MLP(v0B, v1B, rlB, rhB, seB, reB, (tB < real));
            v0A = n0A; v1A = n1A; rlA = nlA; rhA = nhA; seA = nsA; reA = nrA;
            v0B = n0B; v1B = n1B; rlB = nlB; rhB = nhB; seB = nsB; reB = nrB;
            tA = tA2; tB = tB2;
        }
    }
    __syncthreads();

    // ---------- Phase D: f[:,256:352] = z * scale (bf16) ----------
    for (int i = tid; i < 32 * 96; i += 256) {
        int r = i / 96, c = i - r * 96;
        float sc = (c < 32) ? 0.125f : ((c < 64) ? (1.f / 15.f) : (1.f / 16.f));
        f_s[r * 356 + 256 + c] = f2bf(z_s[r * 97 + c] * sc);
    }
    __syncthreads();

    // ---------- Phase E layer1: H = tanh(f @ g_w1 + g_b1) ----------
    #pragma unroll 1
    for (int task = wv; task < 32; task += 4) {
        int mt = task >> 4, nt = task & 15;
        f32x4 acc = {0.f, 0.f, 0.f, 0.f};
        const short* ar = f_s + (mt * 16 + q) * 356 + 8 * g;
        const short* wp = wsb + G1_OFF + nt * 11 * 512 + lane * 8;
        #pragma unroll
        for (int ks = 0; ks < 11; ++ks) {
            s16x4 alo = *(const s16x4*)(ar + 32 * ks);
            s16x4 ahi = *(const s16x4*)(ar + 32 * ks + 4);
            s16x8 a = __builtin_shufflevector(alo, ahi, 0, 1, 2, 3, 4, 5, 6, 7);
            s16x8 bw = *(const s16x8*)(wp + ks * 512);
            acc = mfma32(a, bw, acc);
        }
        float bias = g_b1[nt * 16 + q];
        #pragma unroll
        for (int r = 0; r < 4; ++r)
            H_s[(mt * 16 + 4 * g + r) * 260 + nt * 16 + q] = f2bf(fast_tanh(acc[r] + bias));
    }
    __syncthreads();

    // ---------- Phase E layer2: out = elec + H @ g_w2 + g_b2 ----------
    #pragma unroll 1
    for (int task = wv; task < 32; task += 4) {
        int mt = task >> 4, nt = task & 15;
        f32x4 acc = {0.f, 0.f, 0.f, 0.f};
        const short* ar = H_s + (mt * 16 + q) * 260 + 8 * g;
        const short* wp = wsb + G2_OFF + nt * 8 * 512 + lane * 8;
        #pragma unroll
        for (int ks = 0; ks < 8; ++ks) {
            s16x4 alo = *(const s16x4*)(ar + 32 * ks);
            s16x4 ahi = *(const s16x4*)(ar + 32 * ks + 4);
            s16x8 a = __builtin_shufflevector(alo, ahi, 0, 1, 2, 3, 4, 5, 6, 7);
            s16x8 bw = *(const s16x8*)(wp + ks * 512);
            acc = mfma32(a, bw, acc);
        }
        float bias = g_b2[nt * 16 + q];
        #pragma unroll
        for (int r = 0; r < 4; ++r) {
            int row = mt * 16 + 4 * g + r, col = nt * 16 + q;
            size_t o = ((size_t)b * NE + row) * EMB + col;
            out[o] = bf2f(f_s[row * 356 + col]) + acc[r] + bias;
        }
    }
}

extern "C" void kernel_launch(void* const* d_in, const int* in_sizes, int n_in,
                              void* d_out, int out_size, void* d_ws, size_t ws_size,
                              hipStream_t stream) {
    const float* elec = (const float*)d_in[0];
    const float* nuc  = (const float*)d_in[1];
    const float* fs   = (const float*)d_in[2];
    const float* fa   = (const float*)d_in[3];
    const float* fn   = (const float*)d_in[4];
    const float* u_w1 = (const float*)d_in[5];
    const float* u_b1 = (const float*)d_in[6];
    const float* u_w2 = (const float*)d_in[7];
    const float* u_b2 = (const float*)d_in[8];
    const float* w_w1 = (const float*)d_in[9];
    const float* w_b1 = (const float*)d_in[10];
    const float* w_w2 = (const float*)d_in[11];
    const float* w_b2 = (const float*)d_in[12];
    const float* h_w1 = (const float*)d_in[13];
    const float* h_b1 = (const float*)d_in[14];
    const float* h_w2 = (const float*)d_in[15];
    const float* h_b2 = (const float*)d_in[16];
    const float* g_w1 = (const float*)d_in[17];
    const float* g_b1 = (const float*)d_in[18];
    const float* g_w2 = (const float*)d_in[19];
    const float* g_b2 = (const float*)d_in[20];
    const int* ss = (const int*)d_in[21];
    const int* rs = (const int*)d_in[22];
    const int* sa = (const int*)d_in[23];
    const int* ra = (const int*)d_in[24];
    const int* sn = (const int*)d_in[25];
    const int* rn = (const int*)d_in[26];

    short* wsb = (short*)d_ws;
    int nb = in_sizes[0] / (NE * EMB);

    prep_weights<<<407, 64, 0, stream>>>(u_w1, u_w2, w_w1, w_w2, h_w1, h_w2,
                                         u_b1, u_b2, w_b1, w_b2, h_b1, h_b2,
                                         g_w1, g_w2, wsb);
    gnn_kernel<<<nb, 256, 0, stream>>>(elec, nuc, fs, fa, fn, g_b1, g_b2,
                                       ss, rs, sa, ra, sn, rn, wsb, (float*)d_out);
}

// Round 8
// 484.925 us; speedup vs baseline: 1.1276x; 1.1276x over previous
//
#include <hip/hip_runtime.h>
#include <math.h>

#define NE 32
#define NN 8
#define EMB 256
#define TPS 32
#define E_SAME 480
#define E_ANTI 512
#define E_NE 256

// ---- ws layout (shorts) ----
#define AU1_OFF 0        // 6  x 512 : u_w1^T K=32 A-frags, idx (t*2+mt)
#define AU2_OFF 3072     // 12 x 256 : u_w2^T K=16 A-frags, idx (t*4+mt*2+ks)
#define AW1_OFF 6144     // 12 x 256 : w_w1^T
#define AW2_OFF 9216     // 12 x 256 : w_w2^T
#define H1T_OFF 12288    // 48 x 512 : h_w1^T K=32, idx (t*16+mt*8+ks)
#define H2T_OFF 36864    // 12 x 256 : h_w2^T K=16, idx (t*4+mt*2+ks)
#define BIAS_OFF 39936   // 576 bf16 : [L][t][32], L: u_b1,u_b2,w_b1,w_b2,h_b1,h_b2
#define G1_OFF 40512     // 176 x 512: g_w1 B-frags K=32, idx (nt*11+ks)
#define G2_OFF 130624    // 128 x 512: g_w2 B-frags K=32, idx (nt*8+ks)
// total 196160 shorts = 392320 B

typedef float f32x4 __attribute__((ext_vector_type(4)));
typedef short s16x4 __attribute__((ext_vector_type(4)));
typedef short s16x8 __attribute__((ext_vector_type(8)));

__device__ __forceinline__ short f2bf(float x) {
    unsigned u = __builtin_bit_cast(unsigned, x);
    u += 0x7fffu + ((u >> 16) & 1u);
    return (short)(u >> 16);
}
__device__ __forceinline__ float bf2f(short h) {
    unsigned u = ((unsigned)(unsigned short)h) << 16;
    return __builtin_bit_cast(float, u);
}
__device__ __forceinline__ float fast_tanh(float x) {
    float e = __builtin_amdgcn_exp2f(x * 2.8853900817779268f);
    return 1.f - 2.f * __builtin_amdgcn_rcpf(e + 1.f);
}
__device__ __forceinline__ s16x8 pack8(float4 a, float4 b) {
    s16x8 r = { f2bf(a.x), f2bf(a.y), f2bf(a.z), f2bf(a.w),
                f2bf(b.x), f2bf(b.y), f2bf(b.z), f2bf(b.w) };
    return r;
}
__device__ __forceinline__ f32x4 mfma32(s16x8 a, s16x8 b, f32x4 c) {
    return __builtin_amdgcn_mfma_f32_16x16x32_bf16(a, b, c, 0, 0, 0);
}
// 16x16x16 bf16: C/D layout == B layout -> chained layers need no lane shuffles.
__device__ __forceinline__ f32x4 mfma16(s16x4 a, s16x4 b, f32x4 c) {
#if __has_builtin(__builtin_amdgcn_mfma_f32_16x16x16bf16_1k)
    return __builtin_amdgcn_mfma_f32_16x16x16bf16_1k(a, b, c, 0, 0, 0);
#else
    asm volatile("v_mfma_f32_16x16x16_bf16 %0, %1, %2, %0" : "+v"(c) : "v"(a), "v"(b));
    return c;
#endif
}

__global__ void prep_weights(const float* __restrict__ u_w1, const float* __restrict__ u_w2,
                             const float* __restrict__ w_w1, const float* __restrict__ w_w2,
                             const float* __restrict__ h_w1, const float* __restrict__ h_w2,
                             const float* __restrict__ u_b1, const float* __restrict__ u_b2,
                             const float* __restrict__ w_b1, const float* __restrict__ w_b2,
                             const float* __restrict__ h_b1, const float* __restrict__ h_b2,
                             const float* __restrict__ g_w1, const float* __restrict__ g_w2,
                             short* __restrict__ wsb)
{
    int tile = blockIdx.x, lane = threadIdx.x;
    int g = lane >> 4, q = lane & 15;
    if (tile < 6) {                         // Au1: K=32 A-frag of u_w1^T
        int t = tile >> 1, mt = tile & 1;
        const float* src = u_w1 + t * 1024;
        short* dst = wsb + AU1_OFF + tile * 512 + lane * 8;
        #pragma unroll
        for (int i = 0; i < 8; ++i) dst[i] = f2bf(src[(8 * g + i) * 32 + mt * 16 + q]);
    } else if (tile < 42) {                 // Au2/Aw1/Aw2: K=16 A-frags
        int m = (tile - 6) / 12, idx = (tile - 6) % 12;
        int mt = (idx >> 1) & 1, ks = idx & 1, t = idx >> 2;
        const float* mp = (m == 0) ? u_w2 : (m == 1) ? w_w1 : w_w2;
        const float* src = mp + t * 1024;
        short* dst = wsb + AU2_OFF + m * 3072 + idx * 256 + lane * 4;
        #pragma unroll
        for (int i = 0; i < 4; ++i) dst[i] = f2bf(src[(ks * 16 + 4 * g + i) * 32 + mt * 16 + q]);
    } else if (tile < 90) {                 // h1T: K=32 A-frags
        int idx = tile - 42;
        int t = idx >> 4, r = idx & 15, mt = r >> 3, ks = r & 7;
        const float* src = h_w1 + t * 8192;
        short* dst = wsb + H1T_OFF + idx * 512 + lane * 8;
        #pragma unroll
        for (int i = 0; i < 8; ++i) dst[i] = f2bf(src[(ks * 32 + 8 * g + i) * 32 + mt * 16 + q]);
    } else if (tile < 102) {                // h2T: K=16 A-frags
        int idx = tile - 90;
        int t = idx >> 2, mt = (idx >> 1) & 1, ks = idx & 1;
        const float* src = h_w2 + t * 1024;
        short* dst = wsb + H2T_OFF + idx * 256 + lane * 4;
        #pragma unroll
        for (int i = 0; i < 4; ++i) dst[i] = f2bf(src[(ks * 16 + 4 * g + i) * 32 + mt * 16 + q]);
    } else if (tile == 102) {               // biases -> bf16 [L][t][32]
        const float* bsrc[6] = {u_b1, u_b2, w_b1, w_b2, h_b1, h_b2};
        for (int j = lane; j < 576; j += 64)
            wsb[BIAS_OFF + j] = f2bf(bsrc[j / 96][j % 96]);
    } else if (tile < 279) {                // G1 B-frags
        int idx = tile - 103, nt = idx / 11, ks = idx % 11;
        short* dst = wsb + G1_OFF + idx * 512 + lane * 8;
        #pragma unroll
        for (int i = 0; i < 8; ++i)
            dst[i] = f2bf(g_w1[(size_t)(ks * 32 + 8 * g + i) * 256 + nt * 16 + q]);
    } else {                                // G2 B-frags
        int idx = tile - 279;
        short* dst = wsb + G2_OFF + idx * 512 + lane * 8;
        int nt = idx >> 3, ks = idx & 7;
        #pragma unroll
        for (int i = 0; i < 8; ++i)
            dst[i] = f2bf(g_w2[(size_t)(ks * 32 + 8 * g + i) * 256 + nt * 16 + q]);
    }
}

// LDS (24000 B -> 6 blocks/CU):
//   z_s  f32  [32][97]  @0      (12416 B)
//   hx_s bf16 [72][36]  @12416  (5184 B)
//   f_z  bf16 [32][100] @17600  (6400 B)   z*scale, cols 256..351 of f
//   H_s  bf16 [32][260] @0      (16640 B)  phase-E overlay of z_s+hx_s
__launch_bounds__(256, 4)
__global__ void gnn_kernel(
    const float* __restrict__ elec, const float* __restrict__ nuc,
    const float* __restrict__ fs,  const float* __restrict__ fa,  const float* __restrict__ fn,
    const float* __restrict__ g_b1, const float* __restrict__ g_b2,
    const int* __restrict__ ss, const int* __restrict__ rs,
    const int* __restrict__ sa, const int* __restrict__ ra,
    const int* __restrict__ sn, const int* __restrict__ rn,
    const short* __restrict__ wsb,
    float* __restrict__ out)
{
    __shared__ __align__(16) char smem[24000];
    float* z_s  = (float*)smem;                  // [32][97]
    short* hx_s = (short*)(smem + 12416);        // [72][36]
    short* f_z  = (short*)(smem + 17600);        // [32][100]
    short* H_s  = (short*)smem;                  // [32][260] (phase E overlay)

    const int tid  = threadIdx.x;
    const int b    = blockIdx.x;
    const int lane = tid & 63, wv = tid >> 6;
    const int g    = lane >> 4, q = lane & 15;

    // ---------- Phase A: hx^T = h_w2^T @ tanh(h_w1^T @ X^T + b1) + b2 ----------
    if (wv > 0)
        for (int i = tid - 64; i < 32 * 97; i += 192) z_s[i] = 0.f;

    #pragma unroll 1
    for (int task = wv; task < 5; task += 4) {
        int t, nt;
        if (task < 4) { t = task >> 1; nt = task & 1; }
        else          { t = 2; nt = 0; }
        const float* rowp = (t < 2) ? elec + ((size_t)b * NE + nt * 16 + q) * EMB
                                    : nuc  + ((size_t)b * NN + (q < 8 ? q : 7)) * EMB;
        f32x4 c0 = {0.f, 0.f, 0.f, 0.f}, c1 = {0.f, 0.f, 0.f, 0.f};
        const short* wA = wsb + H1T_OFF + t * 16 * 512;
        #pragma unroll
        for (int ks = 0; ks < 8; ++ks) {
            float4 v0 = *(const float4*)(rowp + 32 * ks + 8 * g);
            float4 v1 = *(const float4*)(rowp + 32 * ks + 8 * g + 4);
            s16x8 Bf = pack8(v0, v1);
            s16x8 a0 = *(const s16x8*)(wA + ks * 512 + lane * 8);
            s16x8 a1 = *(const s16x8*)(wA + (8 + ks) * 512 + lane * 8);
            c0 = mfma32(a0, Bf, c0);
            c1 = mfma32(a1, Bf, c1);
        }
        s16x4 b1l = *(const s16x4*)(wsb + BIAS_OFF + (12 + t) * 32 + 4 * g);
        s16x4 b1h = *(const s16x4*)(wsb + BIAS_OFF + (12 + t) * 32 + 16 + 4 * g);
        s16x4 p0, p1;
        #pragma unroll
        for (int r = 0; r < 4; ++r) {
            p0[r] = f2bf(fast_tanh(c0[r] + bf2f(b1l[r])));
            p1[r] = f2bf(fast_tanh(c1[r] + bf2f(b1h[r])));
        }
        const short* wA2 = wsb + H2T_OFF + t * 4 * 256;
        f32x4 d0 = {0.f, 0.f, 0.f, 0.f}, d1 = {0.f, 0.f, 0.f, 0.f};
        d0 = mfma16(*(const s16x4*)(wA2 + 0 * 256 + lane * 4), p0, d0);
        d0 = mfma16(*(const s16x4*)(wA2 + 1 * 256 + lane * 4), p1, d0);
        d1 = mfma16(*(const s16x4*)(wA2 + 2 * 256 + lane * 4), p0, d1);
        d1 = mfma16(*(const s16x4*)(wA2 + 3 * 256 + lane * 4), p1, d1);
        if (t < 2 || q < 8) {
            s16x4 b2l = *(const s16x4*)(wsb + BIAS_OFF + (15 + t) * 32 + 4 * g);
            s16x4 b2h = *(const s16x4*)(wsb + BIAS_OFF + (15 + t) * 32 + 16 + 4 * g);
            s16x4 w0, w1;
            #pragma unroll
            for (int r = 0; r < 4; ++r) {
                w0[r] = f2bf(d0[r] + bf2f(b2l[r]));
                w1[r] = f2bf(d1[r] + bf2f(b2h[r]));
            }
            int row = t * 32 + nt * 16 + q;
            *(s16x4*)(hx_s + row * 36 + 4 * g)      = w0;
            *(s16x4*)(hx_s + row * 36 + 16 + 4 * g) = w1;
        }
    }
    __syncthreads();

    // ---------- Phase C: edge MLPs, fully register-chained (R6-verified) ----------
    #pragma unroll 1
    for (int t = 0; t < 3; ++t) {
        const float* ft; const int* snd; const int* rcv; int cnt, zc0;
        if (t == 0)      { ft = fs; snd = ss; rcv = rs; cnt = E_SAME; zc0 = 32; }
        else if (t == 1) { ft = fa; snd = sa; rcv = ra; cnt = E_ANTI; zc0 = 64; }
        else             { ft = fn; snd = sn; rcv = rn; cnt = E_NE;   zc0 = 0;  }
        s16x8 Au1_0 = *(const s16x8*)(wsb + AU1_OFF + (t * 2 + 0) * 512 + lane * 8);
        s16x8 Au1_1 = *(const s16x8*)(wsb + AU1_OFF + (t * 2 + 1) * 512 + lane * 8);
        s16x4 Au2_[4], Aw1_[4], Aw2_[4];
        #pragma unroll
        for (int i = 0; i < 4; ++i) {
            Au2_[i] = *(const s16x4*)(wsb + AU2_OFF + (t * 4 + i) * 256 + lane * 4);
            Aw1_[i] = *(const s16x4*)(wsb + AW1_OFF + (t * 4 + i) * 256 + lane * 4);
            Aw2_[i] = *(const s16x4*)(wsb + AW2_OFF + (t * 4 + i) * 256 + lane * 4);
        }
        s16x4 bb1l = *(const s16x4*)(wsb + BIAS_OFF + (0 + t) * 32 + 4 * g);
        s16x4 bb1h = *(const s16x4*)(wsb + BIAS_OFF + (0 + t) * 32 + 16 + 4 * g);
        s16x4 bb2l = *(const s16x4*)(wsb + BIAS_OFF + (3 + t) * 32 + 4 * g);
        s16x4 bb2h = *(const s16x4*)(wsb + BIAS_OFF + (3 + t) * 32 + 16 + 4 * g);
        s16x4 bb3l = *(const s16x4*)(wsb + BIAS_OFF + (6 + t) * 32 + 4 * g);
        s16x4 bb3h = *(const s16x4*)(wsb + BIAS_OFF + (6 + t) * 32 + 16 + 4 * g);
        s16x4 bb4l = *(const s16x4*)(wsb + BIAS_OFF + (9 + t) * 32 + 4 * g);
        s16x4 bb4h = *(const s16x4*)(wsb + BIAS_OFF + (9 + t) * 32 + 16 + 4 * g);
        const short* hxt = hx_s + t * 32 * 36;
        int ntile = cnt >> 4;

        // prologue loads for first tile
        const float* fp = ft + ((size_t)b * cnt + wv * 16 + q) * TPS;
        float4 v0 = *(const float4*)(fp + 8 * g);
        float4 v1 = *(const float4*)(fp + 8 * g + 4);
        float4 rl = *(const float4*)(fp + 4 * g);
        float4 rh = *(const float4*)(fp + 16 + 4 * g);
        int se = snd[wv * 16 + q], re = rcv[wv * 16 + q];

        #pragma unroll 1
        for (int tt = wv; tt < ntile; tt += 4) {
            int tn = tt + 4;
            float4 n0 = {0,0,0,0}, n1 = {0,0,0,0}, nrl = {0,0,0,0}, nrh = {0,0,0,0};
            int ns = 0, nr = 0;
            if (tn < ntile) {   // prefetch next tile
                const float* np = ft + ((size_t)b * cnt + tn * 16 + q) * TPS;
                n0 = *(const float4*)(np + 8 * g);
                n1 = *(const float4*)(np + 8 * g + 4);
                nrl = *(const float4*)(np + 4 * g);
                nrh = *(const float4*)(np + 16 + 4 * g);
                ns = snd[tn * 16 + q]; nr = rcv[tn * 16 + q];
            }
            s16x8 B32 = pack8(v0, v1);
            // u layer1 (K=32)
            f32x4 c0 = {0.f,0.f,0.f,0.f}, c1 = {0.f,0.f,0.f,0.f};
            c0 = mfma32(Au1_0, B32, c0);
            c1 = mfma32(Au1_1, B32, c1);
            s16x4 p0, p1;
            #pragma unroll
            for (int r = 0; r < 4; ++r) {
                p0[r] = f2bf(fast_tanh(c0[r] + bf2f(bb1l[r])));
                p1[r] = f2bf(fast_tanh(c1[r] + bf2f(bb1h[r])));
            }
            // u layer2 (K=16 x2) + residual (f32 feats)
            f32x4 d0 = {0.f,0.f,0.f,0.f}, d1 = {0.f,0.f,0.f,0.f};
            d0 = mfma16(Au2_[0], p0, d0); d0 = mfma16(Au2_[1], p1, d0);
            d1 = mfma16(Au2_[2], p0, d1); d1 = mfma16(Au2_[3], p1, d1);
            const float* rlp = (const float*)&rl; const float* rhp = (const float*)&rh;
            #pragma unroll
            for (int r = 0; r < 4; ++r) {
                p0[r] = f2bf(rlp[r] + d0[r] + bf2f(bb2l[r]));
                p1[r] = f2bf(rhp[r] + d1[r] + bf2f(bb2h[r]));
            }
            // w layer1
            d0 = (f32x4){0.f,0.f,0.f,0.f}; d1 = (f32x4){0.f,0.f,0.f,0.f};
            d0 = mfma16(Aw1_[0], p0, d0); d0 = mfma16(Aw1_[1], p1, d0);
            d1 = mfma16(Aw1_[2], p0, d1); d1 = mfma16(Aw1_[3], p1, d1);
            #pragma unroll
            for (int r = 0; r < 4; ++r) {
                p0[r] = f2bf(fast_tanh(d0[r] + bf2f(bb3l[r])));
                p1[r] = f2bf(fast_tanh(d1[r] + bf2f(bb3h[r])));
            }
            // w layer2 -> we
            d0 = (f32x4){0.f,0.f,0.f,0.f}; d1 = (f32x4){0.f,0.f,0.f,0.f};
            d0 = mfma16(Aw2_[0], p0, d0); d0 = mfma16(Aw2_[1], p1, d0);
            d1 = mfma16(Aw2_[2], p0, d1); d1 = mfma16(Aw2_[3], p1, d1);
            // msg = we * hx[sender] ; scatter into z[receiver]
            s16x4 hlo = *(const s16x4*)(hxt + se * 36 + 4 * g);
            s16x4 hhi = *(const s16x4*)(hxt + se * 36 + 16 + 4 * g);
            float* zr = z_s + re * 97 + zc0 + 4 * g;
            #pragma unroll
            for (int r = 0; r < 4; ++r) {
                atomicAdd(zr + r,      (d0[r] + bf2f(bb4l[r])) * bf2f(hlo[r]));
                atomicAdd(zr + 16 + r, (d1[r] + bf2f(bb4h[r])) * bf2f(hhi[r]));
            }
            v0 = n0; v1 = n1; rl = nrl; rh = nrh; se = ns; re = nr;
        }
    }
    __syncthreads();

    // ---------- Phase D: f_z = z * scale (bf16) ----------
    for (int i = tid; i < 32 * 96; i += 256) {
        int r = i / 96, c = i - r * 96;
        float sc = (c < 32) ? 0.125f : ((c < 64) ? (1.f / 15.f) : (1.f / 16.f));
        f_z[r * 100 + c] = f2bf(z_s[r * 97 + c] * sc);
    }
    __syncthreads();

    // ---------- Phase E layer1: H = tanh(f @ g_w1 + g_b1) ----------
    // elec part of f (cols 0..255) read from global (L2-hot), z part from f_z LDS.
    #pragma unroll 1
    for (int task = wv; task < 32; task += 4) {
        int mt = task >> 4, nt = task & 15;
        f32x4 acc = {0.f, 0.f, 0.f, 0.f};
        const float* erow = elec + ((size_t)b * NE + mt * 16 + q) * EMB + 8 * g;
        const short* zrow = f_z + (mt * 16 + q) * 100 + 8 * g;
        const short* wp = wsb + G1_OFF + nt * 11 * 512 + lane * 8;
        #pragma unroll
        for (int ks = 0; ks < 8; ++ks) {
            float4 v0 = *(const float4*)(erow + 32 * ks);
            float4 v1 = *(const float4*)(erow + 32 * ks + 4);
            s16x8 a = pack8(v0, v1);
            acc = mfma32(a, *(const s16x8*)(wp + ks * 512), acc);
        }
        #pragma unroll
        for (int ks = 8; ks < 11; ++ks) {
            s16x4 alo = *(const s16x4*)(zrow + 32 * (ks - 8));
            s16x4 ahi = *(const s16x4*)(zrow + 32 * (ks - 8) + 4);
            s16x8 a = __builtin_shufflevector(alo, ahi, 0, 1, 2, 3, 4, 5, 6, 7);
            acc = mfma32(a, *(const s16x8*)(wp + ks * 512), acc);
        }
        float bias = g_b1[nt * 16 + q];
        #pragma unroll
        for (int r = 0; r < 4; ++r)
            H_s[(mt * 16 + 4 * g + r) * 260 + nt * 16 + q] = f2bf(fast_tanh(acc[r] + bias));
    }
    __syncthreads();

    // ---------- Phase E layer2: out = elec + H @ g_w2 + g_b2 (f32 residual) ----------
    #pragma unroll 1
    for (int task = wv; task < 32; task += 4) {
        int mt = task >> 4, nt = task & 15;
        f32x4 acc = {0.f, 0.f, 0.f, 0.f};
        const short* ar = H_s + (mt * 16 + q) * 260 + 8 * g;
        const short* wp = wsb + G2_OFF + nt * 8 * 512 + lane * 8;
        #pragma unroll
        for (int ks = 0; ks < 8; ++ks) {
            s16x4 alo = *(const s16x4*)(ar + 32 * ks);
            s16x4 ahi = *(const s16x4*)(ar + 32 * ks + 4);
            s16x8 a = __builtin_shufflevector(alo, ahi, 0, 1, 2, 3, 4, 5, 6, 7);
            s16x8 bw = *(const s16x8*)(wp + ks * 512);
            acc = mfma32(a, bw, acc);
        }
        float bias = g_b2[nt * 16 + q];
        #pragma unroll
        for (int r = 0; r < 4; ++r) {
            int row = mt * 16 + 4 * g + r, col = nt * 16 + q;
            size_t o = ((size_t)b * NE + row) * EMB + col;
            out[o] = elec[o] + acc[r] + bias;
        }
    }
}

extern "C" void kernel_launch(void* const* d_in, const int* in_sizes, int n_in,
                              void* d_out, int out_size, void* d_ws, size_t ws_size,
                              hipStream_t stream) {
    const float* elec = (const float*)d_in[0];
    const float* nuc  = (const float*)d_in[1];
    const float* fs   = (const float*)d_in[2];
    const float* fa   = (const float*)d_in[3];
    const float* fn   = (const float*)d_in[4];
    const float* u_w1 = (const float*)d_in[5];
    const float* u_b1 = (const float*)d_in[6];
    const float* u_w2 = (const float*)d_in[7];
    const float* u_b2 = (const float*)d_in[8];
    const float* w_w1 = (const float*)d_in[9];
    const float* w_b1 = (const float*)d_in[10];
    const float* w_w2 = (const float*)d_in[11];
    const float* w_b2 = (const float*)d_in[12];
    const float* h_w1 = (const float*)d_in[13];
    const float* h_b1 = (const float*)d_in[14];
    const float* h_w2 = (const float*)d_in[15];
    const float* h_b2 = (const float*)d_in[16];
    const float* g_w1 = (const float*)d_in[17];
    const float* g_b1 = (const float*)d_in[18];
    const float* g_w2 = (const float*)d_in[19];
    const float* g_b2 = (const float*)d_in[20];
    const int* ss = (const int*)d_in[21];
    const int* rs = (const int*)d_in[22];
    const int* sa = (const int*)d_in[23];
    const int* ra = (const int*)d_in[24];
    const int* sn = (const int*)d_in[25];
    const int* rn = (const int*)d_in[26];

    short* wsb = (short*)d_ws;
    int nb = in_sizes[0] / (NE * EMB);

    prep_weights<<<407, 64, 0, stream>>>(u_w1, u_w2, w_w1, w_w2, h_w1, h_w2,
                                         u_b1, u_b2, w_b1, w_b2, h_b1, h_b2,
                                         g_w1, g_w2, wsb);
    gnn_kernel<<<nb, 256, 0, stream>>>(elec, nuc, fs, fa, fn, g_b1, g_b2,
                                       ss, rs, sa, ra, sn, rn, wsb, (float*)d_out);
}